// Round 4
// baseline (313.818 us; speedup 1.0000x reference)
//
#include <hip/hip_runtime.h>

#define HW 3136
#define PLANE_ROWS 3440              // padded 58x58=3364 rows + stage-overrun slack
#define PLANE_SHORTS (PLANE_ROWS * 32)

typedef __attribute__((ext_vector_type(4))) float f32x4;
typedef __attribute__((ext_vector_type(8))) short s16x8;
typedef __attribute__((ext_vector_type(8))) __bf16 bf16x8;
typedef unsigned long long ull;
typedef __attribute__((ext_vector_type(2))) ull u64x2;

// ws layout (bytes)
#define XLEV_BYTES ((size_t)256 * PLANE_SHORTS * 2UL)   // 64 b x 4 cb planes ~53.7MB
#define WLEV_OFF   XLEV_BYTES
#define WLEV_BYTES (589824UL * 2UL)
#define POOL_OFF   (WLEV_OFF + WLEV_BYTES)
#define POOL_BYTES (8192UL * 8UL)
#define PAR_OFF    (POOL_OFF + POOL_BYTES)

__device__ __forceinline__ unsigned short f2bf_bits(float f) {
    return (unsigned short)(__float_as_uint(f) >> 16);
}

__device__ __forceinline__ void glds16(const void* g, void* l) {
    __builtin_amdgcn_global_load_lds((const __attribute__((address_space(1))) void*)g,
                                     (__attribute__((address_space(3))) void*)l, 16, 0, 0);
}

// ---------------- pool ----------------
__global__ void pool_kernel(const float* __restrict__ x, double* __restrict__ pooled) {
    int row = blockIdx.x * 4 + (threadIdx.x >> 6);
    int lane = threadIdx.x & 63;
    const float4* xr = (const float4*)(x + (size_t)row * HW);
    double s = 0.0;
    for (int i = lane; i < 784; i += 64) {
        float4 v = xr[i];
        s += (double)v.x + (double)v.y + (double)v.z + (double)v.w;
    }
    for (int off = 32; off; off >>= 1) s += __shfl_down(s, off, 64);
    if (lane == 0) pooled[row] = s / 3136.0;
}

// ---------------- gate ----------------
__global__ void gate_kernel(const double* __restrict__ pooled,
                            const float* __restrict__ fc1, const float* __restrict__ fc2,
                            const float* __restrict__ fc2b, const float* __restrict__ alpha_w,
                            const float* __restrict__ alpha_a,
                            float* __restrict__ params, float* __restrict__ raw_out) {
    int b = blockIdx.x;
    int t = threadIdx.x;
    __shared__ double pl[128];
    __shared__ double hsh[33];
    __shared__ float rawsh[4];
    pl[t]      = pooled[b * 128 + t];
    pl[t + 64] = pooled[b * 128 + 64 + t];
    __syncthreads();
    if (t < 33) {
        double s = 0.0;
        for (int c = 0; c < 128; c++) s += pl[c] * (double)fc1[t * 128 + c];
        hsh[t] = s > 0.0 ? s : 0.0;
    }
    __syncthreads();
    if (t < 4) {
        double s = (double)fc2b[t];
        for (int j = 0; j < 33; j++) s += hsh[j] * (double)fc2[t * 33 + j];
        float r = (float)s;
        rawsh[t] = r;
        raw_out[b * 4 + t] = r;
    }
    __syncthreads();
    if (t == 0) {
        float raw[4];
        for (int k = 0; k < 4; k++) raw[k] = rawsh[k];
        int kb = 0; float mx = raw[0];
        for (int k = 1; k < 4; k++) if (raw[k] > mx) { mx = raw[k]; kb = k; }
        float z[4], m = -1e30f;
        for (int k = 0; k < 4; k++) { z[k] = __fdiv_rn(raw[k], 34.0f); m = fmaxf(m, z[k]); }
        float p[4], sum = 0.0f;
        for (int k = 0; k < 4; k++) {
            p[k] = (float)exp((double)__fsub_rn(z[k], m));
            sum = __fadd_rn(sum, p[k]);
        }
        float s_k   = __fdiv_rn(p[kb], sum);
        float attn1 = __fadd_rn(__fsub_rn(1.0f, s_k), s_k);
        float Qp    = (float)((1 << (kb + 2)) - 1);
        float rQp   = __fmul_rn(attn1, Qp);
        float r_al  = __fmul_rn(attn1, alpha_a[kb]);
        float g_a   = __fdiv_rn(1.0f, __fsqrt_rn(__fmul_rn(401408.0f, rQp)));
        float ta    = __fmul_rn(r_al, g_a);
        float a     = __fadd_rn(__fsub_rn(r_al, ta), ta);
        float Qpw   = (float)((1 << (kb + 1)) - 1);
        float g_w   = __fdiv_rn(1.0f, __fsqrt_rn(__fmul_rn(589824.0f, Qpw)));
        float tw    = __fmul_rn(alpha_w[kb], g_w);
        float aw    = __fadd_rn(__fsub_rn(alpha_w[kb], tw), tw);
        params[b * 8 + 0] = __int_as_float(kb);
        params[b * 8 + 1] = a;
        params[b * 8 + 2] = rQp;
        params[b * 8 + 3] = attn1;
        params[b * 8 + 4] = __fmul_rn(a, aw);
    }
}

// ---------------- weight quant -> wlev [k][tap][cb][o][c'32] ----------------
__global__ void wq_kernel(const float* __restrict__ w, const float* __restrict__ alpha_w,
                          unsigned short* __restrict__ wlev) {
    int id = blockIdx.x * 256 + threadIdx.x;
    int cg = id & 3;
    int o  = (id >> 2) & 127;
    int cb = (id >> 9) & 3;
    int rest = id >> 11;
    int tap = rest % 9, k = rest / 9;
    float Qpw = (float)((1 << (k + 1)) - 1);
    float Qnw = -(float)(1 << (k + 1));
    float g_w = __fdiv_rn(1.0f, __fsqrt_rn(__fmul_rn(589824.0f, Qpw)));
    float tw  = __fmul_rn(alpha_w[k], g_w);
    float aw  = __fadd_rn(__fsub_rn(alpha_w[k], tw), tw);
    const float* wsrc = w + ((size_t)(k * 128 + o) * 128 + cb * 32 + cg * 8) * 9 + tap;
    s16x8 outv;
    for (int j = 0; j < 8; j++) {
        float lv = rintf(fminf(fmaxf(__fdiv_rn(wsrc[j * 9], aw), Qnw), Qpw));
        outv[j] = (short)f2bf_bits(lv);
    }
    *(s16x8*)(wlev + (size_t)id * 8) = outv;
}

// ---------------- zero the padded borders of xlev (re-run every call; ws is poisoned) ----------------
__global__ void zeropad_kernel(unsigned short* __restrict__ xlev) {
    int plane = blockIdx.x;   // 256 planes (b*4+cb)
    unsigned short* pl = xlev + (size_t)plane * PLANE_SHORTS;
    int t = threadIdx.x;      // 256
    // 228 border cells x 16 dwords (64B) each
    for (int i = t; i < 228 * 16; i += 256) {
        int cell = i >> 4, d = i & 15;
        int row;
        if (cell < 58)       row = cell;                        // ph=0
        else if (cell < 116) row = 3306 + (cell - 58);          // ph=57
        else if (cell < 172) row = (cell - 115) * 58;           // pw=0, ph=1..56
        else                 row = (cell - 171) * 58 + 57;      // pw=57, ph=1..56
        ((unsigned int*)(pl + row * 32))[d] = 0u;
    }
}

// ---------------- x quant + transpose -> padded bf16 levels [b][cb][(h+1)*58+(w+1)][c'32] ----------------
__global__ void xq_kernel(const float* __restrict__ x, const float* __restrict__ params,
                          unsigned short* __restrict__ xlev) {
    __shared__ unsigned short lds[64 * 136];
    int b = blockIdx.y, tile = blockIdx.x;
    int p0 = tile * 64;
    float a = params[b * 8 + 1], rQp = params[b * 8 + 2];
    const float* xb = x + (size_t)b * 401408;
    int t = threadIdx.x;
    int cc = t >> 4;
    int p4 = (t & 15) * 4;
    for (int j = 0; j < 8; j++) {
        int c = cc * 8 + j;
        float4 v = *(const float4*)(xb + (size_t)c * HW + p0 + p4);
        float q0 = rintf(fminf(fmaxf(__fdiv_rn(v.x, a), 0.0f), rQp));
        float q1 = rintf(fminf(fmaxf(__fdiv_rn(v.y, a), 0.0f), rQp));
        float q2 = rintf(fminf(fmaxf(__fdiv_rn(v.z, a), 0.0f), rQp));
        float q3 = rintf(fminf(fmaxf(__fdiv_rn(v.w, a), 0.0f), rQp));
        lds[(p4 + 0) * 136 + c] = f2bf_bits(q0);
        lds[(p4 + 1) * 136 + c] = f2bf_bits(q1);
        lds[(p4 + 2) * 136 + c] = f2bf_bits(q2);
        lds[(p4 + 3) * 136 + c] = f2bf_bits(q3);
    }
    __syncthreads();
    int p = t >> 2, seg = t & 3;
    int pix = p0 + p;
    int row = pix + 2 * (pix / 56) + 59;   // (h+1)*58 + (w+1)
    const unsigned short* s = &lds[p * 136];
    unsigned short* dstb = xlev + (size_t)(b * 4) * PLANE_SHORTS + (size_t)row * 32 + seg * 8;
    for (int cb = 0; cb < 4; cb++) {
        *(u64x2*)(dstb + (size_t)cb * PLANE_SHORTS) = *(const u64x2*)(s + cb * 32 + seg * 8);
    }
}

// ---------------- conv: 128x128 tile, B-halo dbuf staging (4 barriers), A streamed via L2 ----------------
__launch_bounds__(256)
__global__ void conv_kernel(const unsigned short* __restrict__ xlev,
                            const unsigned short* __restrict__ wlev,
                            const float* __restrict__ params,
                            const float* __restrict__ bias,
                            float* __restrict__ out) {
    __shared__ unsigned short Bl[2][256 * 32];   // 2 x 16KB halo tiles, 64B rows
    int lid = blockIdx.x + blockIdx.y * 25;
    int xcd = lid & 7, slot = lid >> 3;
    int b = xcd * 8 + slot / 25;
    int tile = slot % 25;
    int p0 = tile * 128;
    int kb = __float_as_int(params[b * 8 + 0]);
    float scale = params[b * 8 + 4], attn1 = params[b * 8 + 3];
    const unsigned short* xp = xlev + (size_t)(b * 4) * PLANE_SHORTS;
    const unsigned short* wb = wlev + (size_t)kb * 9 * 4 * 4096;
    int tid = threadIdx.x;
    int lane = tid & 63, wv = tid >> 6;
    int wm = wv & 1, wn = wv >> 1;
    int q = lane >> 4, l16 = lane & 15;
    int q8 = q * 8;

    int halo_base = (p0 / 56) * 58 + (p0 % 56);

    // per-thread B fragment row bases (constant over taps/cb)
    int rb[4];
    for (int nt = 0; nt < 4; nt++) {
        int pf = p0 + wn * 64 + nt * 16 + l16;
        int h = pf / 56, w = pf - h * 56;
        rb[nt] = (h + 1) * 58 + (w + 1) - halo_base;   // 59..251
    }
    // per-thread A row offsets (shorts)
    int arow[4];
    for (int mt = 0; mt < 4; mt++)
        arow[mt] = (wm * 64 + mt * 16 + l16) * 32 + q8;

    f32x4 acc[4][4] = {};

    // stage B halo for cb into buffer buf: 16KB contiguous
    const unsigned short* gb0 = xp + (size_t)halo_base * 32;
    #define STAGE_B(cbv, buf)                                                      \
        {                                                                          \
            const unsigned short* g = gb0 + (size_t)(cbv) * PLANE_SHORTS;          \
            for (int i = 0; i < 4; i++) {                                          \
                int chunk = wv * 4 + i;                                            \
                glds16(g + chunk * 512 + lane * 8, &Bl[buf][chunk * 512]);         \
            }                                                                      \
        }

    STAGE_B(0, 0);
    for (int cb = 0; cb < 4; cb++) {
        __syncthreads();                 // prev stage visible + prev compute done
        if (cb < 3) STAGE_B(cb + 1, (cb + 1) & 1);
        const unsigned short* Bcur = &Bl[cb & 1][0];
        const unsigned short* wt = wb + cb * 4096;
        for (int t9 = 0; t9 < 9; t9++) {
            int toff = (t9 / 3) * 58 + (t9 % 3) - 59;
            const unsigned short* ab = wt + t9 * 16384;
            s16x8 af[4], bf[4];
            for (int mt = 0; mt < 4; mt++)
                af[mt] = *(const s16x8*)(ab + arow[mt]);
            for (int nt = 0; nt < 4; nt++)
                bf[nt] = *(const s16x8*)(Bcur + (rb[nt] + toff) * 32 + q8);
            for (int mt = 0; mt < 4; mt++)
                for (int nt = 0; nt < 4; nt++)
                    acc[mt][nt] = __builtin_amdgcn_mfma_f32_16x16x32_bf16(
                        __builtin_bit_cast(bf16x8, af[mt]),
                        __builtin_bit_cast(bf16x8, bf[nt]),
                        acc[mt][nt], 0, 0, 0);
        }
    }
    #undef STAGE_B

    const float* bias_k = bias + kb * 128;
    for (int mt = 0; mt < 4; mt++) {
        for (int r = 0; r < 4; r++) {
            int o = wm * 64 + mt * 16 + q * 4 + r;
            float bt = __fmul_rn(attn1, bias_k[o]);
            float* orow = out + ((size_t)b * 128 + o) * 3136;
            for (int nt = 0; nt < 4; nt++) {
                int pf = p0 + wn * 64 + nt * 16 + l16;
                if (pf < 3136)
                    orow[pf] = __fadd_rn(__fmul_rn(scale, acc[mt][nt][r]), bt);
            }
        }
    }
}

extern "C" void kernel_launch(void* const* d_in, const int* in_sizes, int n_in,
                              void* d_out, int out_size, void* d_ws, size_t ws_size,
                              hipStream_t stream) {
    const float* x        = (const float*)d_in[0];
    const float* fc1_w    = (const float*)d_in[1];
    const float* fc2_w    = (const float*)d_in[2];
    const float* fc2_b    = (const float*)d_in[3];
    const float* alpha_w  = (const float*)d_in[4];
    const float* alpha_a  = (const float*)d_in[5];
    const float* weight   = (const float*)d_in[6];
    const float* bias     = (const float*)d_in[7];
    float* out = (float*)d_out;

    char* ws = (char*)d_ws;
    unsigned short* xlev = (unsigned short*)(ws);
    unsigned short* wlev = (unsigned short*)(ws + WLEV_OFF);
    double* pooled       = (double*)(ws + POOL_OFF);
    float* par           = (float*)(ws + PAR_OFF);

    hipLaunchKernelGGL(pool_kernel, dim3(2048), dim3(256), 0, stream, x, pooled);
    hipLaunchKernelGGL(gate_kernel, dim3(64), dim3(64), 0, stream,
                       pooled, fc1_w, fc2_w, fc2_b, alpha_w, alpha_a, par, out + 25690112);
    hipLaunchKernelGGL(wq_kernel, dim3(288), dim3(256), 0, stream, weight, alpha_w, wlev);
    hipLaunchKernelGGL(zeropad_kernel, dim3(256), dim3(256), 0, stream, xlev);
    hipLaunchKernelGGL(xq_kernel, dim3(49, 64), dim3(256), 0, stream, x, par, xlev);
    hipLaunchKernelGGL(conv_kernel, dim3(25, 64), dim3(256), 0, stream, xlev, wlev, par, bias, out);
}

// Round 5
// 285.266 us; speedup vs baseline: 1.1001x; 1.1001x over previous
//
#include <hip/hip_runtime.h>

#define HW 3136
#define PLANE_ROWS 3440              // padded 58x58=3364 rows + stage-overrun slack
#define PLANE_SHORTS (PLANE_ROWS * 32)

typedef __attribute__((ext_vector_type(4))) float f32x4;
typedef __attribute__((ext_vector_type(8))) short s16x8;
typedef __attribute__((ext_vector_type(8))) __bf16 bf16x8;
typedef unsigned long long ull;
typedef __attribute__((ext_vector_type(2))) ull u64x2;

// ws layout (bytes)
#define XLEV_BYTES ((size_t)256 * PLANE_SHORTS * 2UL)   // 64 b x 4 cb planes ~56.4MB
#define WLEV_OFF   XLEV_BYTES
#define WLEV_BYTES (589824UL * 2UL)
#define POOL_OFF   (WLEV_OFF + WLEV_BYTES)
#define POOL_BYTES (8192UL * 8UL)
#define PAR_OFF    (POOL_OFF + POOL_BYTES)

__device__ __forceinline__ unsigned short f2bf_bits(float f) {
    return (unsigned short)(__float_as_uint(f) >> 16);
}

__device__ __forceinline__ void glds16(const void* g, void* l) {
    __builtin_amdgcn_global_load_lds((const __attribute__((address_space(1))) void*)g,
                                     (__attribute__((address_space(3))) void*)l, 16, 0, 0);
}

// ---------------- pool ----------------
__global__ void pool_kernel(const float* __restrict__ x, double* __restrict__ pooled) {
    int row = blockIdx.x * 4 + (threadIdx.x >> 6);
    int lane = threadIdx.x & 63;
    const float4* xr = (const float4*)(x + (size_t)row * HW);
    double s = 0.0;
    for (int i = lane; i < 784; i += 64) {
        float4 v = xr[i];
        s += (double)v.x + (double)v.y + (double)v.z + (double)v.w;
    }
    for (int off = 32; off; off >>= 1) s += __shfl_down(s, off, 64);
    if (lane == 0) pooled[row] = s / 3136.0;
}

// ---------------- gate ----------------
__global__ void gate_kernel(const double* __restrict__ pooled,
                            const float* __restrict__ fc1, const float* __restrict__ fc2,
                            const float* __restrict__ fc2b, const float* __restrict__ alpha_w,
                            const float* __restrict__ alpha_a,
                            float* __restrict__ params, float* __restrict__ raw_out) {
    int b = blockIdx.x;
    int t = threadIdx.x;
    __shared__ double pl[128];
    __shared__ double hsh[33];
    __shared__ float rawsh[4];
    pl[t]      = pooled[b * 128 + t];
    pl[t + 64] = pooled[b * 128 + 64 + t];
    __syncthreads();
    if (t < 33) {
        double s = 0.0;
        for (int c = 0; c < 128; c++) s += pl[c] * (double)fc1[t * 128 + c];
        hsh[t] = s > 0.0 ? s : 0.0;
    }
    __syncthreads();
    if (t < 4) {
        double s = (double)fc2b[t];
        for (int j = 0; j < 33; j++) s += hsh[j] * (double)fc2[t * 33 + j];
        float r = (float)s;
        rawsh[t] = r;
        raw_out[b * 4 + t] = r;
    }
    __syncthreads();
    if (t == 0) {
        float raw[4];
        for (int k = 0; k < 4; k++) raw[k] = rawsh[k];
        int kb = 0; float mx = raw[0];
        for (int k = 1; k < 4; k++) if (raw[k] > mx) { mx = raw[k]; kb = k; }
        float z[4], m = -1e30f;
        for (int k = 0; k < 4; k++) { z[k] = __fdiv_rn(raw[k], 34.0f); m = fmaxf(m, z[k]); }
        float p[4], sum = 0.0f;
        for (int k = 0; k < 4; k++) {
            p[k] = (float)exp((double)__fsub_rn(z[k], m));
            sum = __fadd_rn(sum, p[k]);
        }
        float s_k   = __fdiv_rn(p[kb], sum);
        float attn1 = __fadd_rn(__fsub_rn(1.0f, s_k), s_k);
        float Qp    = (float)((1 << (kb + 2)) - 1);
        float rQp   = __fmul_rn(attn1, Qp);
        float r_al  = __fmul_rn(attn1, alpha_a[kb]);
        float g_a   = __fdiv_rn(1.0f, __fsqrt_rn(__fmul_rn(401408.0f, rQp)));
        float ta    = __fmul_rn(r_al, g_a);
        float a     = __fadd_rn(__fsub_rn(r_al, ta), ta);
        float Qpw   = (float)((1 << (kb + 1)) - 1);
        float g_w   = __fdiv_rn(1.0f, __fsqrt_rn(__fmul_rn(589824.0f, Qpw)));
        float tw    = __fmul_rn(alpha_w[kb], g_w);
        float aw    = __fadd_rn(__fsub_rn(alpha_w[kb], tw), tw);
        params[b * 8 + 0] = __int_as_float(kb);
        params[b * 8 + 1] = a;
        params[b * 8 + 2] = rQp;
        params[b * 8 + 3] = attn1;
        params[b * 8 + 4] = __fmul_rn(a, aw);
    }
}

// ---------------- weight quant -> wlev [k][tap][cb][o][c'32] ----------------
__global__ void wq_kernel(const float* __restrict__ w, const float* __restrict__ alpha_w,
                          unsigned short* __restrict__ wlev) {
    int id = blockIdx.x * 256 + threadIdx.x;
    int cg = id & 3;
    int o  = (id >> 2) & 127;
    int cb = (id >> 9) & 3;
    int rest = id >> 11;
    int tap = rest % 9, k = rest / 9;
    float Qpw = (float)((1 << (k + 1)) - 1);
    float Qnw = -(float)(1 << (k + 1));
    float g_w = __fdiv_rn(1.0f, __fsqrt_rn(__fmul_rn(589824.0f, Qpw)));
    float tw  = __fmul_rn(alpha_w[k], g_w);
    float aw  = __fadd_rn(__fsub_rn(alpha_w[k], tw), tw);
    const float* wsrc = w + ((size_t)(k * 128 + o) * 128 + cb * 32 + cg * 8) * 9 + tap;
    s16x8 outv;
    for (int j = 0; j < 8; j++) {
        float lv = rintf(fminf(fmaxf(__fdiv_rn(wsrc[j * 9], aw), Qnw), Qpw));
        outv[j] = (short)f2bf_bits(lv);
    }
    *(s16x8*)(wlev + (size_t)id * 8) = outv;
}

// ---------------- zero the padded borders of xlev ----------------
__global__ void zeropad_kernel(unsigned short* __restrict__ xlev) {
    int plane = blockIdx.x;   // 256 planes (b*4+cb)
    unsigned short* pl = xlev + (size_t)plane * PLANE_SHORTS;
    int t = threadIdx.x;      // 256
    for (int i = t; i < 228 * 16; i += 256) {
        int cell = i >> 4, d = i & 15;
        int row;
        if (cell < 58)       row = cell;                        // ph=0
        else if (cell < 116) row = 3306 + (cell - 58);          // ph=57
        else if (cell < 172) row = (cell - 115) * 58;           // pw=0, ph=1..56
        else                 row = (cell - 171) * 58 + 57;      // pw=57, ph=1..56
        ((unsigned int*)(pl + row * 32))[d] = 0u;
    }
}

// ---------------- x quant + transpose -> padded bf16 levels [b][cb][(h+1)*58+(w+1)][c'32] ----------------
__global__ void xq_kernel(const float* __restrict__ x, const float* __restrict__ params,
                          unsigned short* __restrict__ xlev) {
    __shared__ unsigned short lds[64 * 136];
    int b = blockIdx.y, tile = blockIdx.x;
    int p0 = tile * 64;
    float a = params[b * 8 + 1], rQp = params[b * 8 + 2];
    const float* xb = x + (size_t)b * 401408;
    int t = threadIdx.x;
    int cc = t >> 4;
    int p4 = (t & 15) * 4;
    for (int j = 0; j < 8; j++) {
        int c = cc * 8 + j;
        float4 v = *(const float4*)(xb + (size_t)c * HW + p0 + p4);
        float q0 = rintf(fminf(fmaxf(__fdiv_rn(v.x, a), 0.0f), rQp));
        float q1 = rintf(fminf(fmaxf(__fdiv_rn(v.y, a), 0.0f), rQp));
        float q2 = rintf(fminf(fmaxf(__fdiv_rn(v.z, a), 0.0f), rQp));
        float q3 = rintf(fminf(fmaxf(__fdiv_rn(v.w, a), 0.0f), rQp));
        lds[(p4 + 0) * 136 + c] = f2bf_bits(q0);
        lds[(p4 + 1) * 136 + c] = f2bf_bits(q1);
        lds[(p4 + 2) * 136 + c] = f2bf_bits(q2);
        lds[(p4 + 3) * 136 + c] = f2bf_bits(q3);
    }
    __syncthreads();
    int p = t >> 2, seg = t & 3;
    int pix = p0 + p;
    int row = pix + 2 * (pix / 56) + 59;   // (h+1)*58 + (w+1)
    const unsigned short* s = &lds[p * 136];
    unsigned short* dstb = xlev + (size_t)(b * 4) * PLANE_SHORTS + (size_t)row * 32 + seg * 8;
    for (int cb = 0; cb < 4; cb++) {
        *(u64x2*)(dstb + (size_t)cb * PLANE_SHORTS) = *(const u64x2*)(s + cb * 32 + seg * 8);
    }
}

// ---------------- conv: 64o x 224p tile, A in registers, B-halo LDS dbuf, 4 barriers ----------------
__launch_bounds__(256, 3)
__global__ void conv_kernel(const unsigned short* __restrict__ xlev,
                            const unsigned short* __restrict__ wlev,
                            const float* __restrict__ params,
                            const float* __restrict__ bias,
                            float* __restrict__ out) {
    __shared__ unsigned short Bl[2][12288];   // 2 x 24KB halo dbuf (384 rows x 64B)
    int lid = blockIdx.x + blockIdx.y * 28;   // grid (28, 64)
    int xcd = lid & 7, slot = lid >> 3;
    int b = xcd * 8 + slot / 28;
    int t28 = slot % 28;
    int ot = t28 & 1, pt = t28 >> 1;          // o-tile 0/1, p-tile 0..13
    int p0 = pt * 224;
    int win = pt * 232;                       // h0*58 = (pt*4)*58, padded-row window base
    int kb = __float_as_int(params[b * 8 + 0]);
    float scale = params[b * 8 + 4], attn1 = params[b * 8 + 3];
    const unsigned short* xp = xlev + (size_t)(b * 4) * PLANE_SHORTS;
    const unsigned short* wb = wlev + (size_t)kb * 147456 + ot * 2048;
    int tid = threadIdx.x, lane = tid & 63, wv = tid >> 6;
    int q = lane >> 4, l16 = lane & 15, q8 = q * 8;

    // B fragment LDS offsets (shorts), window-relative — pt-independent
    int rbs[14];
    #pragma unroll
    for (int nt = 0; nt < 14; nt++) {
        int lp = nt * 16 + l16;               // 0..223
        int lh = lp / 56, lw = lp - lh * 56;
        rbs[nt] = ((lh + 1) * 58 + lw + 1) * 32 + q8;
    }
    int arow = (wv * 16 + l16) * 32 + q8;     // A frag global offset (o-local = wv*16+l16)

    f32x4 acc[14] = {};
    const unsigned short* bwin = xp + (size_t)win * 32;

    // stage B(0): 24KB (6 x 4KB chunks)
    #pragma unroll
    for (int j = 0; j < 6; j++)
        glds16(bwin + j * 2048 + tid * 8, &Bl[0][j * 2048 + wv * 512]);

    #pragma unroll
    for (int cb = 0; cb < 4; cb++) {
        // A fragments for all 9 taps -> registers (drained by the barrier below)
        s16x8 af[9];
        const unsigned short* wcb = wb + cb * 4096;
        #pragma unroll
        for (int t9 = 0; t9 < 9; t9++)
            af[t9] = *(const s16x8*)(wcb + t9 * 16384 + arow);
        __syncthreads();                       // B(cb) visible (vmcnt drained pre-barrier)
        if (cb < 3) {                          // prefetch B(cb+1) into other buffer
            const unsigned short* bn = bwin + (size_t)(cb + 1) * PLANE_SHORTS;
            #pragma unroll
            for (int j = 0; j < 6; j++)
                glds16(bn + j * 2048 + tid * 8, &Bl[(cb + 1) & 1][j * 2048 + wv * 512]);
        }
        const unsigned short* Bc = &Bl[cb & 1][0];
        #pragma unroll
        for (int t9 = 0; t9 < 9; t9++) {
            const int toffs = ((t9 / 3) * 58 + (t9 % 3) - 59) * 32;
            #pragma unroll
            for (int nt = 0; nt < 14; nt++) {
                s16x8 bf = *(const s16x8*)(Bc + rbs[nt] + toffs);
                acc[nt] = __builtin_amdgcn_mfma_f32_16x16x32_bf16(
                    __builtin_bit_cast(bf16x8, af[t9]),
                    __builtin_bit_cast(bf16x8, bf), acc[nt], 0, 0, 0);
            }
        }
    }

    // epilogue: out = fl(scale*acc_int) + fl(attn1*bias) — no masking (224|3136, o<128)
    const float* bias_k = bias + kb * 128;
    int obase = ot * 64 + wv * 16 + q * 4;
    float bt[4];
    #pragma unroll
    for (int r = 0; r < 4; r++) bt[r] = __fmul_rn(attn1, bias_k[obase + r]);
    #pragma unroll
    for (int r = 0; r < 4; r++) {
        float* orow = out + ((size_t)b * 128 + obase + r) * 3136;
        #pragma unroll
        for (int nt = 0; nt < 14; nt++) {
            int pf = p0 + nt * 16 + l16;
            orow[pf] = __fadd_rn(__fmul_rn(scale, acc[nt][r]), bt[r]);
        }
    }
}

extern "C" void kernel_launch(void* const* d_in, const int* in_sizes, int n_in,
                              void* d_out, int out_size, void* d_ws, size_t ws_size,
                              hipStream_t stream) {
    const float* x        = (const float*)d_in[0];
    const float* fc1_w    = (const float*)d_in[1];
    const float* fc2_w    = (const float*)d_in[2];
    const float* fc2_b    = (const float*)d_in[3];
    const float* alpha_w  = (const float*)d_in[4];
    const float* alpha_a  = (const float*)d_in[5];
    const float* weight   = (const float*)d_in[6];
    const float* bias     = (const float*)d_in[7];
    float* out = (float*)d_out;

    char* ws = (char*)d_ws;
    unsigned short* xlev = (unsigned short*)(ws);
    unsigned short* wlev = (unsigned short*)(ws + WLEV_OFF);
    double* pooled       = (double*)(ws + POOL_OFF);
    float* par           = (float*)(ws + PAR_OFF);

    hipLaunchKernelGGL(pool_kernel, dim3(2048), dim3(256), 0, stream, x, pooled);
    hipLaunchKernelGGL(gate_kernel, dim3(64), dim3(64), 0, stream,
                       pooled, fc1_w, fc2_w, fc2_b, alpha_w, alpha_a, par, out + 25690112);
    hipLaunchKernelGGL(wq_kernel, dim3(288), dim3(256), 0, stream, weight, alpha_w, wlev);
    hipLaunchKernelGGL(zeropad_kernel, dim3(256), dim3(256), 0, stream, xlev);
    hipLaunchKernelGGL(xq_kernel, dim3(49, 64), dim3(256), 0, stream, x, par, xlev);
    hipLaunchKernelGGL(conv_kernel, dim3(28, 64), dim3(256), 0, stream, xlev, wlev, par, bias, out);
}

// Round 6
// 282.761 us; speedup vs baseline: 1.1098x; 1.0089x over previous
//
#include <hip/hip_runtime.h>

#define HW 3136
#define KP_ROWS 3440                     // padded 58x58=3364 rows + stage-overrun slack
#define KP_SHORTS (KP_ROWS * 16)         // one kh half-plane = 55040 shorts (32B rows)
#define CB_SHORTS (2 * KP_SHORTS)        // per (b,cb): 110080 shorts
#define B_SHORTS  (4 * CB_SHORTS)        // per b: 440320 shorts

typedef __attribute__((ext_vector_type(4))) float f32x4;
typedef __attribute__((ext_vector_type(16))) float f32x16;
typedef __attribute__((ext_vector_type(8))) short s16x8;
typedef __attribute__((ext_vector_type(8))) __bf16 bf16x8;
typedef unsigned long long ull;
typedef __attribute__((ext_vector_type(2))) ull u64x2;

// ws layout (bytes)
#define XLEV_BYTES ((size_t)64 * B_SHORTS * 2UL)        // ~56.4MB
#define WLEV_OFF   XLEV_BYTES
#define WLEV_BYTES (589824UL * 2UL)
#define POOL_OFF   (WLEV_OFF + WLEV_BYTES)
#define POOL_BYTES (8192UL * 8UL)
#define PAR_OFF    (POOL_OFF + POOL_BYTES)

__device__ __forceinline__ unsigned short f2bf_bits(float f) {
    return (unsigned short)(__float_as_uint(f) >> 16);
}

__device__ __forceinline__ void glds16(const void* g, void* l) {
    __builtin_amdgcn_global_load_lds((const __attribute__((address_space(1))) void*)g,
                                     (__attribute__((address_space(3))) void*)l, 16, 0, 0);
}

// ---------------- fused prep: pool (2048 blk) + wq (288 blk) + zeropad (256 blk) ----------------
__global__ void prep_kernel(const float* __restrict__ x, const float* __restrict__ w,
                            const float* __restrict__ alpha_w,
                            double* __restrict__ pooled, unsigned short* __restrict__ wlev,
                            unsigned short* __restrict__ xlev) {
    int bid = blockIdx.x;
    int t = threadIdx.x;
    if (bid < 2048) {
        // pool: pooled[b][c] = mean (f64 accumulate)
        int row = bid * 4 + (t >> 6);
        int lane = t & 63;
        const float4* xr = (const float4*)(x + (size_t)row * HW);
        double s = 0.0;
        for (int i = lane; i < 784; i += 64) {
            float4 v = xr[i];
            s += (double)v.x + (double)v.y + (double)v.z + (double)v.w;
        }
        for (int off = 32; off; off >>= 1) s += __shfl_down(s, off, 64);
        if (lane == 0) pooled[row] = s / 3136.0;
    } else if (bid < 2336) {
        // wq -> wlev [k][tap][cb][o][c'32]
        int id = (bid - 2048) * 256 + t;
        int cg = id & 3;
        int o  = (id >> 2) & 127;
        int cb = (id >> 9) & 3;
        int rest = id >> 11;
        int tap = rest % 9, k = rest / 9;
        float Qpw = (float)((1 << (k + 1)) - 1);
        float Qnw = -(float)(1 << (k + 1));
        float g_w = __fdiv_rn(1.0f, __fsqrt_rn(__fmul_rn(589824.0f, Qpw)));
        float tw  = __fmul_rn(alpha_w[k], g_w);
        float aw  = __fadd_rn(__fsub_rn(alpha_w[k], tw), tw);
        const float* wsrc = w + ((size_t)(k * 128 + o) * 128 + cb * 32 + cg * 8) * 9 + tap;
        s16x8 outv;
        for (int j = 0; j < 8; j++) {
            float lv = rintf(fminf(fmaxf(__fdiv_rn(wsrc[j * 9], aw), Qnw), Qpw));
            outv[j] = (short)f2bf_bits(lv);
        }
        *(s16x8*)(wlev + (size_t)id * 8) = outv;
    } else {
        // zeropad borders of xlev: plane = (b,cb), zero both kh half-planes
        int plane = bid - 2336;   // 0..255
        unsigned short* pl = xlev + (size_t)plane * CB_SHORTS;
        for (int i = t; i < 228 * 8; i += 256) {
            int cell = i >> 3, d = i & 7;
            int row;
            if (cell < 58)       row = cell;                        // ph=0
            else if (cell < 116) row = 3306 + (cell - 58);          // ph=57
            else if (cell < 172) row = (cell - 115) * 58;           // pw=0
            else                 row = (cell - 171) * 58 + 57;      // pw=57
            ((unsigned int*)(pl + row * 16))[d] = 0u;
            ((unsigned int*)(pl + KP_SHORTS + row * 16))[d] = 0u;
        }
    }
}

// ---------------- gate: 64 blocks (one per batch), 64 threads ----------------
__global__ void gate_kernel(const double* __restrict__ pooled,
                            const float* __restrict__ fc1, const float* __restrict__ fc2,
                            const float* __restrict__ fc2b, const float* __restrict__ alpha_w,
                            const float* __restrict__ alpha_a,
                            float* __restrict__ params, float* __restrict__ raw_out) {
    int b = blockIdx.x;
    int t = threadIdx.x;
    __shared__ double pl[128];
    __shared__ double hsh[33];
    __shared__ float rawsh[4];
    pl[t]      = pooled[b * 128 + t];
    pl[t + 64] = pooled[b * 128 + 64 + t];
    __syncthreads();
    if (t < 33) {
        double s = 0.0;
        for (int c = 0; c < 128; c++) s += pl[c] * (double)fc1[t * 128 + c];
        hsh[t] = s > 0.0 ? s : 0.0;
    }
    __syncthreads();
    if (t < 4) {
        double s = (double)fc2b[t];
        for (int j = 0; j < 33; j++) s += hsh[j] * (double)fc2[t * 33 + j];
        float r = (float)s;
        rawsh[t] = r;
        raw_out[b * 4 + t] = r;
    }
    __syncthreads();
    if (t == 0) {
        float raw[4];
        for (int k = 0; k < 4; k++) raw[k] = rawsh[k];
        int kb = 0; float mx = raw[0];
        for (int k = 1; k < 4; k++) if (raw[k] > mx) { mx = raw[k]; kb = k; }
        float z[4], m = -1e30f;
        for (int k = 0; k < 4; k++) { z[k] = __fdiv_rn(raw[k], 34.0f); m = fmaxf(m, z[k]); }
        float p[4], sum = 0.0f;
        for (int k = 0; k < 4; k++) {
            p[k] = (float)exp((double)__fsub_rn(z[k], m));
            sum = __fadd_rn(sum, p[k]);
        }
        float s_k   = __fdiv_rn(p[kb], sum);
        float attn1 = __fadd_rn(__fsub_rn(1.0f, s_k), s_k);
        float Qp    = (float)((1 << (kb + 2)) - 1);
        float rQp   = __fmul_rn(attn1, Qp);
        float r_al  = __fmul_rn(attn1, alpha_a[kb]);
        float g_a   = __fdiv_rn(1.0f, __fsqrt_rn(__fmul_rn(401408.0f, rQp)));
        float ta    = __fmul_rn(r_al, g_a);
        float a     = __fadd_rn(__fsub_rn(r_al, ta), ta);
        float Qpw   = (float)((1 << (kb + 1)) - 1);
        float g_w   = __fdiv_rn(1.0f, __fsqrt_rn(__fmul_rn(589824.0f, Qpw)));
        float tw    = __fmul_rn(alpha_w[kb], g_w);
        float aw    = __fadd_rn(__fsub_rn(alpha_w[kb], tw), tw);
        params[b * 8 + 0] = __int_as_float(kb);
        params[b * 8 + 1] = a;
        params[b * 8 + 2] = rQp;
        params[b * 8 + 3] = attn1;
        params[b * 8 + 4] = __fmul_rn(a, aw);
    }
}

// ---------------- x quant + transpose -> padded kh-split levels [b][cb][kh][row][c'16] ----------------
__global__ void xq_kernel(const float* __restrict__ x, const float* __restrict__ params,
                          unsigned short* __restrict__ xlev) {
    __shared__ unsigned short lds[64 * 136];
    int b = blockIdx.y, tile = blockIdx.x;
    int p0 = tile * 64;
    float a = params[b * 8 + 1], rQp = params[b * 8 + 2];
    const float* xb = x + (size_t)b * 401408;
    int t = threadIdx.x;
    int cc = t >> 4;
    int p4 = (t & 15) * 4;
    for (int j = 0; j < 8; j++) {
        int c = cc * 8 + j;
        float4 v = *(const float4*)(xb + (size_t)c * HW + p0 + p4);
        float q0 = rintf(fminf(fmaxf(__fdiv_rn(v.x, a), 0.0f), rQp));
        float q1 = rintf(fminf(fmaxf(__fdiv_rn(v.y, a), 0.0f), rQp));
        float q2 = rintf(fminf(fmaxf(__fdiv_rn(v.z, a), 0.0f), rQp));
        float q3 = rintf(fminf(fmaxf(__fdiv_rn(v.w, a), 0.0f), rQp));
        lds[(p4 + 0) * 136 + c] = f2bf_bits(q0);
        lds[(p4 + 1) * 136 + c] = f2bf_bits(q1);
        lds[(p4 + 2) * 136 + c] = f2bf_bits(q2);
        lds[(p4 + 3) * 136 + c] = f2bf_bits(q3);
    }
    __syncthreads();
    int p = t >> 2, seg = t & 3;     // seg -> kh=seg>>1, half=seg&1
    int pix = p0 + p;
    int row = pix + 2 * (pix / 56) + 59;   // (h+1)*58 + (w+1)
    const unsigned short* s = &lds[p * 136];
    unsigned short* dstb = xlev + (size_t)b * B_SHORTS + (size_t)(seg >> 1) * KP_SHORTS
                          + (size_t)row * 16 + (seg & 1) * 8;
    for (int cb = 0; cb < 4; cb++) {
        *(u64x2*)(dstb + (size_t)cb * CB_SHORTS) = *(const u64x2*)(s + cb * 32 + seg * 8);
    }
}

// ---------------- conv: 128o x 224p tile, 32x32x16 MFMA, kh-split LDS, A in regs ----------------
__launch_bounds__(256)
__global__ void conv_kernel(const unsigned short* __restrict__ xlev,
                            const unsigned short* __restrict__ wlev,
                            const float* __restrict__ params,
                            const float* __restrict__ bias,
                            float* __restrict__ out) {
    __shared__ unsigned short Bl[2][12288];   // [buf][kh(2) x 384rows x 16sh] = 2x24KB
    int lid = blockIdx.x + blockIdx.y * 14;   // grid (14, 64)
    int xcd = lid & 7, slot = lid >> 3;       // 112 slots
    int b = xcd * 8 + slot / 14;
    int pt = slot % 14;
    int p0 = pt * 224;
    int winrow = pt * 232;                    // (pt*4)*58
    int kb = __float_as_int(params[b * 8 + 0]);
    float scale = params[b * 8 + 4], attn1 = params[b * 8 + 3];
    const unsigned short* xb = xlev + (size_t)b * B_SHORTS;
    const unsigned short* wb = wlev + (size_t)kb * 147456;
    int tid = threadIdx.x, lane = tid & 63, wv = tid >> 6;
    int l32 = lane & 31, h = lane >> 5;

    // B-frag offsets (shorts) within one kh half-plane of the LDS buffer
    int rbs[7];
    #pragma unroll
    for (int nt = 0; nt < 7; nt++) {
        int lp = nt * 32 + l32;               // 0..223
        int lh = lp / 56, lw = lp - lh * 56;
        rbs[nt] = ((lh + 1) * 58 + lw + 1) * 16 + h * 8;
    }
    int arow = (wv * 32 + l32) * 32 + h * 8;  // + cb*4096 + kh*16 + tap*16384

    f32x16 acc[7] = {};
    const unsigned short* bwin = xb + winrow * 16;   // cb=0, kh=0 window base

    // stage cb: 2 kh-planes x 3 chunks of 4KB (256 lanes x 16B)
    #define STAGE_B(cbv, buf)                                                      \
        {                                                                          \
            const unsigned short* g = bwin + (size_t)(cbv) * CB_SHORTS;            \
            for (int j2 = 0; j2 < 6; j2++) {                                       \
                int kh2 = j2 >> 1, j = j2 & 1;                                     \
                (void)j;                                                           \
                glds16(g + (j2 >> 1) * KP_SHORTS + (j2 & 1 ? 2048 : 0) * 1 +       \
                           ((j2 & 1) ? 0 : 0), nullptr);                           \
            }                                                                      \
        }
    #undef STAGE_B
    // (macro above unused — explicit staging below for clarity)

    {   // stage cb=0 into buf 0
        const unsigned short* g = bwin;
        #pragma unroll
        for (int kh2 = 0; kh2 < 2; kh2++)
            #pragma unroll
            for (int j = 0; j < 3; j++)
                glds16(g + kh2 * KP_SHORTS + j * 2048 + tid * 8,
                       &Bl[0][kh2 * 6144 + j * 2048 + wv * 512]);
    }

    #pragma unroll
    for (int cb = 0; cb < 4; cb++) {
        __syncthreads();                      // stage(cb) visible
        if (cb < 3) {
            const unsigned short* g = bwin + (size_t)(cb + 1) * CB_SHORTS;
            #pragma unroll
            for (int kh2 = 0; kh2 < 2; kh2++)
                #pragma unroll
                for (int j = 0; j < 3; j++)
                    glds16(g + kh2 * KP_SHORTS + j * 2048 + tid * 8,
                           &Bl[(cb + 1) & 1][kh2 * 6144 + j * 2048 + wv * 512]);
        }
        const unsigned short* Bc = &Bl[cb & 1][0];
        const unsigned short* wcb = wb + cb * 4096;
        #pragma unroll
        for (int kh = 0; kh < 2; kh++) {
            s16x8 af[9];
            #pragma unroll
            for (int t9 = 0; t9 < 9; t9++)
                af[t9] = *(const s16x8*)(wcb + t9 * 16384 + kh * 16 + arow);
            const unsigned short* Bk = Bc + kh * 6144;
            #pragma unroll
            for (int t9 = 0; t9 < 9; t9++) {
                const int toffs = ((t9 / 3) * 58 + (t9 % 3) - 59) * 16;
                #pragma unroll
                for (int nt = 0; nt < 7; nt++) {
                    s16x8 bf = *(const s16x8*)(Bk + rbs[nt] + toffs);
                    acc[nt] = __builtin_amdgcn_mfma_f32_32x32x16_bf16(
                        __builtin_bit_cast(bf16x8, af[t9]),
                        __builtin_bit_cast(bf16x8, bf), acc[nt], 0, 0, 0);
                }
            }
        }
    }

    // epilogue: o = wv*32 + (reg&3) + 8*(reg>>2) + 4*h ; p = p0 + nt*32 + l32
    const float* bias_k = bias + kb * 128;
    int ob = wv * 32 + 4 * h;
    #pragma unroll
    for (int reg = 0; reg < 16; reg++) {
        int o = ob + (reg & 3) + 8 * (reg >> 2);
        float bt = __fmul_rn(attn1, bias_k[o]);
        float* orow = out + ((size_t)b * 128 + o) * 3136 + p0 + l32;
        #pragma unroll
        for (int nt = 0; nt < 7; nt++)
            orow[nt * 32] = __fadd_rn(__fmul_rn(scale, acc[nt][reg]), bt);
    }
}

extern "C" void kernel_launch(void* const* d_in, const int* in_sizes, int n_in,
                              void* d_out, int out_size, void* d_ws, size_t ws_size,
                              hipStream_t stream) {
    const float* x        = (const float*)d_in[0];
    const float* fc1_w    = (const float*)d_in[1];
    const float* fc2_w    = (const float*)d_in[2];
    const float* fc2_b    = (const float*)d_in[3];
    const float* alpha_w  = (const float*)d_in[4];
    const float* alpha_a  = (const float*)d_in[5];
    const float* weight   = (const float*)d_in[6];
    const float* bias     = (const float*)d_in[7];
    float* out = (float*)d_out;

    char* ws = (char*)d_ws;
    unsigned short* xlev = (unsigned short*)(ws);
    unsigned short* wlev = (unsigned short*)(ws + WLEV_OFF);
    double* pooled       = (double*)(ws + POOL_OFF);
    float* par           = (float*)(ws + PAR_OFF);

    hipLaunchKernelGGL(prep_kernel, dim3(2592), dim3(256), 0, stream,
                       x, weight, alpha_w, pooled, wlev, xlev);
    hipLaunchKernelGGL(gate_kernel, dim3(64), dim3(64), 0, stream,
                       pooled, fc1_w, fc2_w, fc2_b, alpha_w, alpha_a, par, out + 25690112);
    hipLaunchKernelGGL(xq_kernel, dim3(49, 64), dim3(256), 0, stream, x, par, xlev);
    hipLaunchKernelGGL(conv_kernel, dim3(14, 64), dim3(256), 0, stream, xlev, wlev, par, bias, out);
}